// Round 6
// baseline (52.881 us; speedup 1.0000x reference)
//
#include <hip/hip_runtime.h>

// Problem constants (from the JAX reference)
constexpr int B = 4;
constexpr int L = 4096;
constexpr int D = 2048;
constexpr float EPS = 1e-5f;

constexpr int CL = 16;          // output rows per block
constexpr int NR = CL + 3;      // rows loaded incl. 3-row causal halo = 19
constexpr int NW = 8;           // waves per block (512 threads)
constexpr int NCHUNK = L / CL;  // 256
constexpr int NWG = NCHUNK * B; // 1024 blocks (divisible by 8 XCDs)

typedef float floatx4 __attribute__((ext_vector_type(4)));

// ---------------------------------------------------------------------------
// Fully fused: RMSNorm -> causal depthwise conv (K=4) -> SiLU, single pass,
// ONE barrier per block. All 19 rows live in registers; 19 float4 loads in
// flight per thread from the start (max MLP), 19 independent shfl-reduce
// chains, one __syncthreads, then normalize/conv/SiLU/store.
// ---------------------------------------------------------------------------
__global__ __launch_bounds__(512, 4) void fused_kernel(const float* __restrict__ x,
                                                       const float* __restrict__ nw,
                                                       const float* __restrict__ cw,
                                                       float* __restrict__ out) {
    const int t = threadIdx.x;          // 0..511
    const int wave = t >> 6;
    const int lane = t & 63;

    // XCD-aware swizzle: consecutive work ids (adjacent L-chunks, sharing
    // halo rows) land on the same XCD's L2. NWG % 8 == 0 -> bijective.
    const int bid = blockIdx.x;
    const int swz = (bid & 7) * (NWG / 8) + (bid >> 3);
    const int b = swz / NCHUNK;
    const int chunk = swz % NCHUNK;
    const int l0 = chunk * CL;
    const int d = t * 4;

    const float* xb = x + (size_t)b * L * D + d;
    float* ob = out + (size_t)b * L * D + d;

    __shared__ __align__(16) float s_red[NR][NW];   // 608 B

    // Load weights; fold norm_weight into conv weights: wn[k] = cw[k,:]*nw
    const floatx4 nwv = *reinterpret_cast<const floatx4*>(nw + d);
    floatx4 wn[4];
    #pragma unroll
    for (int k = 0; k < 4; ++k)
        wn[k] = *reinterpret_cast<const floatx4*>(cw + k * D + d) * nwv;

    // ---- Phase 1: issue ALL row loads, then 19 independent reduces ----
    floatx4 hx[NR];
    #pragma unroll
    for (int j = 0; j < NR; ++j) {
        const int l = l0 - 3 + j;
        if (l >= 0)
            hx[j] = *reinterpret_cast<const floatx4*>(xb + (size_t)l * D);
        else
            hx[j] = (floatx4)0.0f;
    }

    #pragma unroll
    for (int j = 0; j < NR; ++j) {
        float s = hx[j].x * hx[j].x + hx[j].y * hx[j].y
                + hx[j].z * hx[j].z + hx[j].w * hx[j].w;
        #pragma unroll
        for (int off = 32; off > 0; off >>= 1)
            s += __shfl_down(s, off, 64);
        if (lane == 0) s_red[j][wave] = s;
    }

    __syncthreads();   // the ONLY barrier

    // ---- Phase 2a: normalize rows in place (LDS partials via 2x b128) ----
    #pragma unroll
    for (int j = 0; j < NR; ++j) {
        floatx4 p0 = *reinterpret_cast<const floatx4*>(&s_red[j][0]);
        floatx4 p1 = *reinterpret_cast<const floatx4*>(&s_red[j][4]);
        float tot = ((p0.x + p0.y) + (p0.z + p0.w))
                  + ((p1.x + p1.y) + (p1.z + p1.w));
        const float irms = rsqrtf(tot * (1.0f / D) + EPS);
        hx[j] *= irms;
    }

    // ---- Phase 2b: K=4 causal conv + SiLU + nt-store ----
    #pragma unroll
    for (int li = 0; li < CL; ++li) {
        floatx4 y = wn[0] * hx[li]     + wn[1] * hx[li + 1]
                  + wn[2] * hx[li + 2] + wn[3] * hx[li + 3];
        floatx4 sg;
        sg.x = 1.0f / (1.0f + __expf(-y.x));
        sg.y = 1.0f / (1.0f + __expf(-y.y));
        sg.z = 1.0f / (1.0f + __expf(-y.z));
        sg.w = 1.0f / (1.0f + __expf(-y.w));
        y *= sg;
        __builtin_nontemporal_store(y,
            reinterpret_cast<floatx4*>(ob + (size_t)(l0 + li) * D));
    }
}

extern "C" void kernel_launch(void* const* d_in, const int* in_sizes, int n_in,
                              void* d_out, int out_size, void* d_ws, size_t ws_size,
                              hipStream_t stream) {
    const float* x  = (const float*)d_in[0];   // (B, L, D) fp32
    const float* nw = (const float*)d_in[1];   // (D,) fp32
    const float* cw = (const float*)d_in[2];   // (K, 1, D) fp32
    float* out = (float*)d_out;                // (B, L, D) fp32

    fused_kernel<<<NWG, 512, 0, stream>>>(x, nw, cw, out);
}